// Round 7
// baseline (115.774 us; speedup 1.0000x reference)
//
#include <hip/hip_runtime.h>
#include <hip/hip_cooperative_groups.h>

namespace cg = cooperative_groups;

// TopKRouter: x[B=16,C=768,H=64,W=64] fp32, W[E=16,C=768], b[E=16], k=2.
// R7: single COOPERATIVE kernel. Phase A: blocks 0..47 transpose W -> Wt[C][E]
// in ws (coalesced read, tiny scattered write). grid.sync(). Phase B: R4's
// proven main loop (float2/lane, 4 channel-groups x 128 px/block, Wt via
// wave-uniform s_load) with unroll 8 for a deeper load pipeline.
// Outputs fp32 concat: topk_probs[16,2,64,64] | topk_indices[16,2,64,64] |
// scores[16,16,64,64].

#define C_DIM 768
#define E_DIM 16
#define HW    4096   // 64*64
#define NPIX  65536  // 16*4096

__global__ __launch_bounds__(256, 2) void router_coop(
    const float* __restrict__ x,     // [B, C, HW]
    const float* __restrict__ Wm,    // [E, C]
    const float* __restrict__ bias,  // [E]
    float* __restrict__ out,
    float* __restrict__ Wt)          // ws: [C, E]
{
    __shared__ float lds[4][128][17];  // [cg][px][e], pad 17 -> conflict-free

    // ---- Phase A: W transpose into ws (blocks 0..47) ----
    {
        const int idx = blockIdx.x * 256 + threadIdx.x;  // linear over Wm [E][C]
        if (idx < C_DIM * E_DIM) {
            const int e = idx / C_DIM;
            const int c = idx - e * C_DIM;
            Wt[c * E_DIM + e] = Wm[idx];  // read coalesced, write scattered (12K stores)
        }
    }
    cg::this_grid().sync();

    // ---- Phase B: main (R4 structure) ----
    const int p0  = blockIdx.x * 128;            // first pixel of block
    const int b   = p0 >> 12;                    // batch (block-uniform)
    const int pb  = p0 & 4095;
    const int cg_ = __builtin_amdgcn_readfirstlane(threadIdx.x >> 6);
    const int px2 = threadIdx.x & 63;            // lane -> pixel pair
    const int c0  = cg_ * 192;

    const float* xp = x + (size_t)b * C_DIM * HW + pb + 2 * px2;

    float2 acc[E_DIM];
#pragma unroll
    for (int e = 0; e < E_DIM; ++e) acc[e] = make_float2(0.f, 0.f);

#pragma unroll 8
    for (int c = c0; c < c0 + 192; ++c) {
        const float2 xv = *reinterpret_cast<const float2*>(xp + (size_t)c * HW);
        const float4* wt = reinterpret_cast<const float4*>(Wt + c * E_DIM);
        const float4 w0 = wt[0], w1 = wt[1], w2 = wt[2], w3 = wt[3];
        acc[ 0].x = fmaf(xv.x, w0.x, acc[ 0].x); acc[ 0].y = fmaf(xv.y, w0.x, acc[ 0].y);
        acc[ 1].x = fmaf(xv.x, w0.y, acc[ 1].x); acc[ 1].y = fmaf(xv.y, w0.y, acc[ 1].y);
        acc[ 2].x = fmaf(xv.x, w0.z, acc[ 2].x); acc[ 2].y = fmaf(xv.y, w0.z, acc[ 2].y);
        acc[ 3].x = fmaf(xv.x, w0.w, acc[ 3].x); acc[ 3].y = fmaf(xv.y, w0.w, acc[ 3].y);
        acc[ 4].x = fmaf(xv.x, w1.x, acc[ 4].x); acc[ 4].y = fmaf(xv.y, w1.x, acc[ 4].y);
        acc[ 5].x = fmaf(xv.x, w1.y, acc[ 5].x); acc[ 5].y = fmaf(xv.y, w1.y, acc[ 5].y);
        acc[ 6].x = fmaf(xv.x, w1.z, acc[ 6].x); acc[ 6].y = fmaf(xv.y, w1.z, acc[ 6].y);
        acc[ 7].x = fmaf(xv.x, w1.w, acc[ 7].x); acc[ 7].y = fmaf(xv.y, w1.w, acc[ 7].y);
        acc[ 8].x = fmaf(xv.x, w2.x, acc[ 8].x); acc[ 8].y = fmaf(xv.y, w2.x, acc[ 8].y);
        acc[ 9].x = fmaf(xv.x, w2.y, acc[ 9].x); acc[ 9].y = fmaf(xv.y, w2.y, acc[ 9].y);
        acc[10].x = fmaf(xv.x, w2.z, acc[10].x); acc[10].y = fmaf(xv.y, w2.z, acc[10].y);
        acc[11].x = fmaf(xv.x, w2.w, acc[11].x); acc[11].y = fmaf(xv.y, w2.w, acc[11].y);
        acc[12].x = fmaf(xv.x, w3.x, acc[12].x); acc[12].y = fmaf(xv.y, w3.x, acc[12].y);
        acc[13].x = fmaf(xv.x, w3.y, acc[13].x); acc[13].y = fmaf(xv.y, w3.y, acc[13].y);
        acc[14].x = fmaf(xv.x, w3.z, acc[14].x); acc[14].y = fmaf(xv.y, w3.z, acc[14].y);
        acc[15].x = fmaf(xv.x, w3.w, acc[15].x); acc[15].y = fmaf(xv.y, w3.w, acc[15].y);
    }

    // stage partials: [cg][pixel][e] (stride 17 -> 2 lanes/bank, free)
#pragma unroll
    for (int e = 0; e < E_DIM; ++e) {
        lds[cg_][2 * px2][e]     = acc[e].x;
        lds[cg_][2 * px2 + 1][e] = acc[e].y;
    }
    __syncthreads();

    const int t = threadIdx.x;
    if (t < 128) {
        const int p = pb + t;  // pixel within b-plane

        float lg[E_DIM];
#pragma unroll
        for (int e = 0; e < E_DIM; ++e)
            lg[e] = bias[e] + lds[0][t][e] + lds[1][t][e] + lds[2][t][e] + lds[3][t][e];

        float m = -INFINITY;
#pragma unroll
        for (int e = 0; e < E_DIM; ++e) m = fmaxf(m, lg[e]);
        float pr[E_DIM];
        float sum = 0.0f;
#pragma unroll
        for (int e = 0; e < E_DIM; ++e) {
            pr[e] = __expf(lg[e] - m);
            sum += pr[e];
        }
        const float inv = 1.0f / sum;

        float* scores = out + 262144;
#pragma unroll
        for (int e = 0; e < E_DIM; ++e) {
            const float s = pr[e] * inv;
            pr[e] = s;
            scores[(size_t)(b * E_DIM + e) * HW + p] = s;
        }

        // top-2, ties -> lower index (matches jax.lax.top_k)
        int i1 = 0;
        float p1 = pr[0];
#pragma unroll
        for (int e = 1; e < E_DIM; ++e)
            if (pr[e] > p1) { p1 = pr[e]; i1 = e; }
        int i2 = -1;
        float p2 = -INFINITY;
#pragma unroll
        for (int e = 0; e < E_DIM; ++e)
            if (e != i1 && pr[e] > p2) { p2 = pr[e]; i2 = e; }

        const float rs = 1.0f / (p1 + p2);
        const size_t o1 = (size_t)(b * 2 + 0) * HW + p;
        const size_t o2 = (size_t)(b * 2 + 1) * HW + p;
        out[o1] = p1 * rs;
        out[o2] = p2 * rs;
        float* idxo = out + 131072;
        idxo[o1] = (float)i1;
        idxo[o2] = (float)i2;
    }
}

// ---------------- Fallback: two-kernel (if coop launch unavailable) -------
__global__ __launch_bounds__(256) void transpose_w(
    const float* __restrict__ Wm, float* __restrict__ Wt)
{
    const int idx = blockIdx.x * 256 + threadIdx.x;
    if (idx < C_DIM * E_DIM) {
        const int e = idx / C_DIM;
        const int c = idx - e * C_DIM;
        Wt[c * E_DIM + e] = Wm[idx];
    }
}

__global__ __launch_bounds__(256, 2) void router_main(
    const float* __restrict__ x, const float* __restrict__ Wt,
    const float* __restrict__ bias, float* __restrict__ out)
{
    __shared__ float lds[4][128][17];
    const int p0  = blockIdx.x * 128;
    const int b   = p0 >> 12;
    const int pb  = p0 & 4095;
    const int cg_ = __builtin_amdgcn_readfirstlane(threadIdx.x >> 6);
    const int px2 = threadIdx.x & 63;
    const int c0  = cg_ * 192;
    const float* xp = x + (size_t)b * C_DIM * HW + pb + 2 * px2;

    float2 acc[E_DIM];
#pragma unroll
    for (int e = 0; e < E_DIM; ++e) acc[e] = make_float2(0.f, 0.f);
#pragma unroll 8
    for (int c = c0; c < c0 + 192; ++c) {
        const float2 xv = *reinterpret_cast<const float2*>(xp + (size_t)c * HW);
        const float4* wt = reinterpret_cast<const float4*>(Wt + c * E_DIM);
        const float4 w0 = wt[0], w1 = wt[1], w2 = wt[2], w3 = wt[3];
        acc[ 0].x = fmaf(xv.x, w0.x, acc[ 0].x); acc[ 0].y = fmaf(xv.y, w0.x, acc[ 0].y);
        acc[ 1].x = fmaf(xv.x, w0.y, acc[ 1].x); acc[ 1].y = fmaf(xv.y, w0.y, acc[ 1].y);
        acc[ 2].x = fmaf(xv.x, w0.z, acc[ 2].x); acc[ 2].y = fmaf(xv.y, w0.z, acc[ 2].y);
        acc[ 3].x = fmaf(xv.x, w0.w, acc[ 3].x); acc[ 3].y = fmaf(xv.y, w0.w, acc[ 3].y);
        acc[ 4].x = fmaf(xv.x, w1.x, acc[ 4].x); acc[ 4].y = fmaf(xv.y, w1.x, acc[ 4].y);
        acc[ 5].x = fmaf(xv.x, w1.y, acc[ 5].x); acc[ 5].y = fmaf(xv.y, w1.y, acc[ 5].y);
        acc[ 6].x = fmaf(xv.x, w1.z, acc[ 6].x); acc[ 6].y = fmaf(xv.y, w1.z, acc[ 6].y);
        acc[ 7].x = fmaf(xv.x, w1.w, acc[ 7].x); acc[ 7].y = fmaf(xv.y, w1.w, acc[ 7].y);
        acc[ 8].x = fmaf(xv.x, w2.x, acc[ 8].x); acc[ 8].y = fmaf(xv.y, w2.x, acc[ 8].y);
        acc[ 9].x = fmaf(xv.x, w2.y, acc[ 9].x); acc[ 9].y = fmaf(xv.y, w2.y, acc[ 9].y);
        acc[10].x = fmaf(xv.x, w2.z, acc[10].x); acc[10].y = fmaf(xv.y, w2.z, acc[10].y);
        acc[11].x = fmaf(xv.x, w2.w, acc[11].x); acc[11].y = fmaf(xv.y, w2.w, acc[11].y);
        acc[12].x = fmaf(xv.x, w3.x, acc[12].x); acc[12].y = fmaf(xv.y, w3.x, acc[12].y);
        acc[13].x = fmaf(xv.x, w3.y, acc[13].x); acc[13].y = fmaf(xv.y, w3.y, acc[13].y);
        acc[14].x = fmaf(xv.x, w3.z, acc[14].x); acc[14].y = fmaf(xv.y, w3.z, acc[14].y);
        acc[15].x = fmaf(xv.x, w3.w, acc[15].x); acc[15].y = fmaf(xv.y, w3.w, acc[15].y);
    }
#pragma unroll
    for (int e = 0; e < E_DIM; ++e) {
        lds[cg_][2 * px2][e]     = acc[e].x;
        lds[cg_][2 * px2 + 1][e] = acc[e].y;
    }
    __syncthreads();
    const int t = threadIdx.x;
    if (t < 128) {
        const int p = pb + t;
        float lg[E_DIM];
#pragma unroll
        for (int e = 0; e < E_DIM; ++e)
            lg[e] = bias[e] + lds[0][t][e] + lds[1][t][e] + lds[2][t][e] + lds[3][t][e];
        float m = -INFINITY;
#pragma unroll
        for (int e = 0; e < E_DIM; ++e) m = fmaxf(m, lg[e]);
        float pr[E_DIM]; float sum = 0.0f;
#pragma unroll
        for (int e = 0; e < E_DIM; ++e) { pr[e] = __expf(lg[e] - m); sum += pr[e]; }
        const float inv = 1.0f / sum;
        float* scores = out + 262144;
#pragma unroll
        for (int e = 0; e < E_DIM; ++e) {
            const float s = pr[e] * inv; pr[e] = s;
            scores[(size_t)(b * E_DIM + e) * HW + p] = s;
        }
        int i1 = 0; float p1 = pr[0];
#pragma unroll
        for (int e = 1; e < E_DIM; ++e) if (pr[e] > p1) { p1 = pr[e]; i1 = e; }
        int i2 = -1; float p2 = -INFINITY;
#pragma unroll
        for (int e = 0; e < E_DIM; ++e) if (e != i1 && pr[e] > p2) { p2 = pr[e]; i2 = e; }
        const float rs = 1.0f / (p1 + p2);
        const size_t o1 = (size_t)(b * 2 + 0) * HW + p;
        const size_t o2 = (size_t)(b * 2 + 1) * HW + p;
        out[o1] = p1 * rs; out[o2] = p2 * rs;
        float* idxo = out + 131072;
        idxo[o1] = (float)i1; idxo[o2] = (float)i2;
    }
}

extern "C" void kernel_launch(void* const* d_in, const int* in_sizes, int n_in,
                              void* d_out, int out_size, void* d_ws, size_t ws_size,
                              hipStream_t stream) {
    const float* x  = (const float*)d_in[0];
    const float* Wm = (const float*)d_in[1];
    const float* bs = (const float*)d_in[2];
    float* out = (float*)d_out;
    float* Wt  = (float*)d_ws;  // 48 KB

    if (ws_size >= (size_t)C_DIM * E_DIM * sizeof(float)) {
        void* args[] = {(void*)&x, (void*)&Wm, (void*)&bs, (void*)&out, (void*)&Wt};
        hipError_t err = hipLaunchCooperativeKernel(
            (const void*)router_coop, dim3(NPIX / 128), dim3(256), args, 0, stream);
        if (err != hipSuccess) {
            // fallback: two-kernel path (R4)
            transpose_w<<<48, 256, 0, stream>>>(Wm, Wt);
            router_main<<<NPIX / 128, 256, 0, stream>>>(x, Wt, bs, out);
        }
    } else {
        // no usable ws: two-kernel impossible; transpose into nothing -> use
        // direct (slow) path via router_main reading Wm? Not valid. Fall back
        // to cooperative-less two-kernel requires ws; as last resort, launch
        // transpose into a static dummy is unsafe — instead do nothing-fancy:
        // (ws is known-large in this harness; this branch is defensive.)
        transpose_w<<<48, 256, 0, stream>>>(Wm, (float*)d_ws);
        router_main<<<NPIX / 128, 256, 0, stream>>>(x, (float*)d_ws, bs, out);
    }
}

// Round 8
// 40.715 us; speedup vs baseline: 2.8435x; 2.8435x over previous
//
#include <hip/hip_runtime.h>

// TopKRouter: x[B=16,C=768,H=64,W=64] fp32, W[E=16,C=768], b[E=16], k=2.
// R8 = R4 (proven 41.3us: separate Wt-transpose prologue so main kernel's Wt
// reads stay wave-uniform s_load broadcasts — R7 showed same-kernel Wt
// production demotes them to vector loads, 146us) + two levers:
//   1. unroll 8 channel loop (deeper load pipeline)
//   2. chunked XCD swizzle: logical block = (bid&7)*64 + (bid>>3) puts each
//      b-plane's 32 blocks on one XCD -> full 16KB x[b,c,:] row streamed per
//      channel step per XCD (DRAM burst locality).
// Outputs fp32 concat: topk_probs[16,2,64,64] | topk_indices[16,2,64,64] |
// scores[16,16,64,64].

#define C_DIM 768
#define E_DIM 16
#define HW    4096   // 64*64
#define NPIX  65536  // 16*4096

// ---------------- Prologue: Wt[c][e] = W[e][c] ----------------------------
__global__ __launch_bounds__(256) void transpose_w(
    const float* __restrict__ Wm, float* __restrict__ Wt)
{
    const int t = blockIdx.x * 256 + threadIdx.x;  // 12288 elements
    if (t < C_DIM * E_DIM) {
        const int e = t / C_DIM;
        const int c = t - e * C_DIM;
        Wt[c * E_DIM + e] = Wm[t];  // coalesced read, scattered write
    }
}

// ---------------- Main ----------------------------------------------------
__global__ __launch_bounds__(256) void router_main(
    const float* __restrict__ x,     // [B, C, HW]
    const float* __restrict__ Wt,    // [C, E] transposed weights (in ws)
    const float* __restrict__ bias,  // [E]
    float* __restrict__ out)
{
    __shared__ float lds[4][128][17];  // [cg][px][e], pad 17 -> conflict-free

    // chunked XCD swizzle (512 blocks, 8 XCDs, 64 chunks each) — bijective
    const int logical = ((blockIdx.x & 7) << 6) + (blockIdx.x >> 3);

    const int p0  = logical * 128;               // first pixel of block
    const int b   = p0 >> 12;                    // batch (block-uniform)
    const int pb  = p0 & 4095;
    const int cg  = __builtin_amdgcn_readfirstlane(threadIdx.x >> 6);
    const int px2 = threadIdx.x & 63;            // lane -> pixel pair
    const int c0  = cg * 192;

    const float* xp = x + (size_t)b * C_DIM * HW + pb + 2 * px2;

    float2 acc[E_DIM];
#pragma unroll
    for (int e = 0; e < E_DIM; ++e) acc[e] = make_float2(0.f, 0.f);

#pragma unroll 8
    for (int c = c0; c < c0 + 192; ++c) {
        const float2 xv = *reinterpret_cast<const float2*>(xp + (size_t)c * HW);
        const float4* wt = reinterpret_cast<const float4*>(Wt + c * E_DIM);
        const float4 w0 = wt[0], w1 = wt[1], w2 = wt[2], w3 = wt[3];
        acc[ 0].x = fmaf(xv.x, w0.x, acc[ 0].x); acc[ 0].y = fmaf(xv.y, w0.x, acc[ 0].y);
        acc[ 1].x = fmaf(xv.x, w0.y, acc[ 1].x); acc[ 1].y = fmaf(xv.y, w0.y, acc[ 1].y);
        acc[ 2].x = fmaf(xv.x, w0.z, acc[ 2].x); acc[ 2].y = fmaf(xv.y, w0.z, acc[ 2].y);
        acc[ 3].x = fmaf(xv.x, w0.w, acc[ 3].x); acc[ 3].y = fmaf(xv.y, w0.w, acc[ 3].y);
        acc[ 4].x = fmaf(xv.x, w1.x, acc[ 4].x); acc[ 4].y = fmaf(xv.y, w1.x, acc[ 4].y);
        acc[ 5].x = fmaf(xv.x, w1.y, acc[ 5].x); acc[ 5].y = fmaf(xv.y, w1.y, acc[ 5].y);
        acc[ 6].x = fmaf(xv.x, w1.z, acc[ 6].x); acc[ 6].y = fmaf(xv.y, w1.z, acc[ 6].y);
        acc[ 7].x = fmaf(xv.x, w1.w, acc[ 7].x); acc[ 7].y = fmaf(xv.y, w1.w, acc[ 7].y);
        acc[ 8].x = fmaf(xv.x, w2.x, acc[ 8].x); acc[ 8].y = fmaf(xv.y, w2.x, acc[ 8].y);
        acc[ 9].x = fmaf(xv.x, w2.y, acc[ 9].x); acc[ 9].y = fmaf(xv.y, w2.y, acc[ 9].y);
        acc[10].x = fmaf(xv.x, w2.z, acc[10].x); acc[10].y = fmaf(xv.y, w2.z, acc[10].y);
        acc[11].x = fmaf(xv.x, w2.w, acc[11].x); acc[11].y = fmaf(xv.y, w2.w, acc[11].y);
        acc[12].x = fmaf(xv.x, w3.x, acc[12].x); acc[12].y = fmaf(xv.y, w3.x, acc[12].y);
        acc[13].x = fmaf(xv.x, w3.y, acc[13].x); acc[13].y = fmaf(xv.y, w3.y, acc[13].y);
        acc[14].x = fmaf(xv.x, w3.z, acc[14].x); acc[14].y = fmaf(xv.y, w3.z, acc[14].y);
        acc[15].x = fmaf(xv.x, w3.w, acc[15].x); acc[15].y = fmaf(xv.y, w3.w, acc[15].y);
    }

    // stage partials: [cg][pixel][e] (stride 17 -> 2 lanes/bank, free)
#pragma unroll
    for (int e = 0; e < E_DIM; ++e) {
        lds[cg][2 * px2][e]     = acc[e].x;
        lds[cg][2 * px2 + 1][e] = acc[e].y;
    }
    __syncthreads();

    const int t = threadIdx.x;
    if (t < 128) {
        const int p = pb + t;  // pixel within b-plane

        float lg[E_DIM];
#pragma unroll
        for (int e = 0; e < E_DIM; ++e)
            lg[e] = bias[e] + lds[0][t][e] + lds[1][t][e] + lds[2][t][e] + lds[3][t][e];

        float m = -INFINITY;
#pragma unroll
        for (int e = 0; e < E_DIM; ++e) m = fmaxf(m, lg[e]);
        float pr[E_DIM];
        float sum = 0.0f;
#pragma unroll
        for (int e = 0; e < E_DIM; ++e) {
            pr[e] = __expf(lg[e] - m);
            sum += pr[e];
        }
        const float inv = 1.0f / sum;

        float* scores = out + 262144;
#pragma unroll
        for (int e = 0; e < E_DIM; ++e) {
            const float s = pr[e] * inv;
            pr[e] = s;
            scores[(size_t)(b * E_DIM + e) * HW + p] = s;
        }

        // top-2, ties -> lower index (matches jax.lax.top_k)
        int i1 = 0;
        float p1 = pr[0];
#pragma unroll
        for (int e = 1; e < E_DIM; ++e)
            if (pr[e] > p1) { p1 = pr[e]; i1 = e; }
        int i2 = -1;
        float p2 = -INFINITY;
#pragma unroll
        for (int e = 0; e < E_DIM; ++e)
            if (e != i1 && pr[e] > p2) { p2 = pr[e]; i2 = e; }

        const float rs = 1.0f / (p1 + p2);
        const size_t o1 = (size_t)(b * 2 + 0) * HW + p;
        const size_t o2 = (size_t)(b * 2 + 1) * HW + p;
        out[o1] = p1 * rs;
        out[o2] = p2 * rs;
        float* idxo = out + 131072;
        idxo[o1] = (float)i1;
        idxo[o2] = (float)i2;
    }
}

// ---------------- Fallback: fused single-pass, no ws ----------------------
__global__ __launch_bounds__(256) void topk_router_fused(
    const float* __restrict__ x, const float* __restrict__ Wm,
    const float* __restrict__ bias, float* __restrict__ out)
{
    const int g = blockIdx.x * 256 + threadIdx.x;
    const int b = g >> 12;
    const int p = g & 4095;
    const float* xp = x + (size_t)b * C_DIM * HW + p;

    float acc[E_DIM];
#pragma unroll
    for (int e = 0; e < E_DIM; ++e) acc[e] = 0.0f;
#pragma unroll 16
    for (int c = 0; c < C_DIM; ++c) {
        const float xv = xp[(size_t)c * HW];
#pragma unroll
        for (int e = 0; e < E_DIM; ++e)
            acc[e] = fmaf(xv, Wm[e * C_DIM + c], acc[e]);
    }
    float m = -INFINITY;
#pragma unroll
    for (int e = 0; e < E_DIM; ++e) { acc[e] += bias[e]; m = fmaxf(m, acc[e]); }
    float pr[E_DIM]; float sum = 0.0f;
#pragma unroll
    for (int e = 0; e < E_DIM; ++e) { pr[e] = __expf(acc[e] - m); sum += pr[e]; }
    const float inv = 1.0f / sum;
    float* scores = out + 262144;
#pragma unroll
    for (int e = 0; e < E_DIM; ++e) {
        const float s = pr[e] * inv; pr[e] = s;
        scores[(size_t)(b * E_DIM + e) * HW + p] = s;
    }
    int i1 = 0; float p1 = pr[0];
#pragma unroll
    for (int e = 1; e < E_DIM; ++e) if (pr[e] > p1) { p1 = pr[e]; i1 = e; }
    int i2 = -1; float p2 = -INFINITY;
#pragma unroll
    for (int e = 0; e < E_DIM; ++e) if (e != i1 && pr[e] > p2) { p2 = pr[e]; i2 = e; }
    const float rs = 1.0f / (p1 + p2);
    const size_t o1 = (size_t)(b * 2 + 0) * HW + p;
    const size_t o2 = (size_t)(b * 2 + 1) * HW + p;
    out[o1] = p1 * rs; out[o2] = p2 * rs;
    float* idxo = out + 131072;
    idxo[o1] = (float)i1; idxo[o2] = (float)i2;
}

extern "C" void kernel_launch(void* const* d_in, const int* in_sizes, int n_in,
                              void* d_out, int out_size, void* d_ws, size_t ws_size,
                              hipStream_t stream) {
    const float* x  = (const float*)d_in[0];
    const float* Wm = (const float*)d_in[1];
    const float* bs = (const float*)d_in[2];
    float* out = (float*)d_out;
    float* Wt  = (float*)d_ws;  // 48 KB

    if (ws_size >= (size_t)C_DIM * E_DIM * sizeof(float)) {
        transpose_w<<<48, 256, 0, stream>>>(Wm, Wt);
        router_main<<<NPIX / 128, 256, 0, stream>>>(x, Wt, bs, out);
    } else {
        topk_router_fused<<<NPIX / 256, 256, 0, stream>>>(x, Wm, bs, out);
    }
}